// Round 13
// baseline (398.484 us; speedup 1.0000x reference)
//
#include <hip/hip_runtime.h>

// ---------------------------------------------------------------- constants
#define T_N   262144
#define D_IN  128
#define A_DIM 8
#define GAMMA 0.99f
#define EPS_C 0.2f
#define C_GL  0.9405f                 // GAMMA*LMBD
#define HALF_LOG_2PI 0.9189385332f
#define SCALE2 2.8853900817779268f    // 2*log2(e): pre-activation scale for exp2-tanh
#define ST_TPB 8                      // state tiles (32 rows) per block
#define NX_TPB 4                      // next tiles (64 rows) per block
#define HB_S   20                     // sh_hb padded stride (floats)

typedef __attribute__((ext_vector_type(8))) short short8;
typedef __attribute__((ext_vector_type(4))) float f32x4;

__device__ __forceinline__ unsigned short f2bf(float f) {   // RNE (prep only)
  unsigned int u = __float_as_uint(f);
  u += 0x7FFFu + ((u >> 16) & 1u);
  return (unsigned short)(u >> 16);
}
// pack two f32 -> two bf16 (truncate) in ONE v_perm_b32
__device__ __forceinline__ unsigned int pack_bf2(float lo, float hi) {
  return __builtin_amdgcn_perm(__float_as_uint(hi), __float_as_uint(lo), 0x07060302u);
}
__device__ __forceinline__ unsigned short bf_trunc(float f) {
  return (unsigned short)(__float_as_uint(f) >> 16);
}
// a = 2*log2(e)*x (weights pre-scaled); returns tanh(x).
__device__ __forceinline__ float tanh_pre(float a) {
  float e = __builtin_amdgcn_exp2f(a);
  return 1.f - 2.f * __builtin_amdgcn_rcpf(e + 1.f);
}
template <int CTRL>
__device__ __forceinline__ float dpp_add(float p) {
  return p + __int_as_float(__builtin_amdgcn_update_dpp(
                 0, __float_as_int(p), CTRL, 0xF, 0xF, true));
}
// sum over each 16-lane row; total lands at lane%16 == 15
__device__ __forceinline__ float row16_sum(float p) {
  p = dpp_add<0x111>(p); p = dpp_add<0x112>(p);
  p = dpp_add<0x114>(p); p = dpp_add<0x118>(p);
  return p;
}
// sum over each 8-lane group; total at all 8 lanes (xor1, xor2, half-mirror)
__device__ __forceinline__ float xor8_sum(float p) {
  p = dpp_add<0xB1>(p); p = dpp_add<0x4E>(p); p = dpp_add<0x141>(p);
  return p;
}

// ---------------------------------------------------------------- prep:
// Wc1Ts/W1Ts: [H][D] bf16, transposed AND pre-scaled by 2*log2(e).
// H1: [16][256] bf16 actor head (rows0-7 = Wmu^T, 8-15 = Wlv^T). Also zeros accs.
__global__ __launch_bounds__(256) void k_prep(
    const float* __restrict__ Wc1, const float* __restrict__ W1,
    const float* __restrict__ Wmu, const float* __restrict__ Wlv,
    unsigned short* __restrict__ Wc1Ts, unsigned short* __restrict__ W1Ts,
    unsigned short* __restrict__ H1, float* __restrict__ accs) {
  int i = blockIdx.x * 256 + threadIdx.x;
  if (blockIdx.x == 0 && threadIdx.x < 8) ((unsigned int*)accs)[threadIdx.x] = 0u;
  if (i < 32768) {
    int n = i >> 7, k = i & 127;
    Wc1Ts[i] = f2bf(Wc1[k * 256 + n] * SCALE2);
  } else if (i < 65536) {
    int j = i - 32768; int n = j >> 7, k = j & 127;
    W1Ts[j] = f2bf(W1[k * 256 + n] * SCALE2);
  } else if (i < 69632) {
    int j = i - 65536; int h = j >> 8, n = j & 255;
    H1[j] = (h < 8) ? f2bf(Wmu[n * 8 + h]) : f2bf(Wlv[n * 8 + (h - 8)]);
  }
}

// ---------------------------------------------------------------- k_main:
// 1024 blocks x 512 threads; two SEQUENTIAL phases per block (every block does
// both -> no R2-style role imbalance):
//   phase 1 (R0-exact k_state, measured 93 us): 8 tiles of 32 state rows.
//     waves 0-3 critic->v0 (fused VALU head); waves 4-7 actor hidden -> head
//     MFMA (4-way K-split) -> sh_hb -> 256-thread ratio epilogue. 3 barriers.
//   phase 2 (R2-validated next path): 4 tiles of 64 next_state rows; 8 waves
//     = 2 row-halves x 4 col-slices of critic->v1. 2 barriers/tile.
// Critic waves reuse Wc1Ts bfrag across phases; actor waves reload from
// L2-hot Wc1Ts. Merging deletes one launch boundary and lets early-finishing
// blocks start phase 2 while others finish phase 1 (tail fill).
// LDS union: phase1 sh_x[0,8704)+sh_h[8704,25600)+sh_hb[25600,35840)+
// sh_v[35840,36352); phase2 sh_x2[0,17408)+sh_v2[17408,18432). Transition
// safety: post-barrier3 epilogue reads only sh_hb/globals; phase-2 staging
// writes [0,17408) -- disjoint.
__global__ __launch_bounds__(512, 4) void k_main(
    const float* __restrict__ state, const float* __restrict__ next_state,
    const float* __restrict__ action, const float* __restrict__ beta_lp,
    const unsigned short* __restrict__ Wc1Ts, const unsigned short* __restrict__ W1Ts,
    const unsigned short* __restrict__ H1,
    const float* __restrict__ bc1, const float* __restrict__ b1,
    const float* __restrict__ Wc2, const float* __restrict__ bc2,
    const float* __restrict__ bmu, const float* __restrict__ blv,
    float* __restrict__ v0out, float* __restrict__ v1out,
    float* __restrict__ ratio) {
  const int tid  = threadIdx.x;
  const int lane = tid & 63;
  const int wv   = tid >> 6;          // 0..7
  const int role = wv >> 2;           // 0 = critic, 1 = actor
  const int wl   = wv & 3;            // slice within role
  const int c    = lane & 15;
  const int quad = lane >> 4;

  __shared__ __align__(16) char smem[36352];
  unsigned short* sh_x  = (unsigned short*)smem;              //  8704 B
  unsigned short* sh_h  = (unsigned short*)(smem + 8704);     // 16896 B
  float*          sh_hb = (float*)(smem + 25600);             // 10240 B
  float*          sh_v  = (float*)(smem + 35840);             //   512 B
  unsigned short* sh_x2 = (unsigned short*)smem;              // 17408 B
  float*          sh_v2 = (float*)(smem + 17408);             //  1024 B

  const unsigned short* WT = role ? W1Ts : Wc1Ts;
  const float* bias = role ? b1 : bc1;

  short8 bfrag[4][4];
  float bias_c[4], wc2_c[4];
#pragma unroll
  for (int ct = 0; ct < 4; ++ct) {
    int n = wl * 64 + ct * 16 + c;
    bias_c[ct] = bias[n] * SCALE2;
    wc2_c[ct]  = Wc2[n];
#pragma unroll
    for (int ki = 0; ki < 4; ++ki)
      bfrag[ct][ki] = *(const short8*)(WT + n * 128 + ki * 32 + quad * 8);
  }
  const float vbias = bc2[0];
  const int aa = tid & 7;
  const float bmu_a = bmu[aa], blv_a = blv[aa];

  // ================= phase 1: state =================
  const int t0 = blockIdx.x * ST_TPB;

  float4 rbuf[2];
  {
    const float4* Xv = (const float4*)(state + (size_t)t0 * 32 * D_IN);
    rbuf[0] = Xv[tid]; rbuf[1] = Xv[tid + 512];
  }

  for (int i = 0; i < ST_TPB; ++i) {
    const int r0 = (t0 + i) * 32;

    // ---- stage regs -> LDS bf16 (perm-truncate: 1 op / 2 elems)
#pragma unroll
    for (int j = 0; j < 2; ++j) {
      int e4 = tid + j * 512;
      int row = e4 >> 5, c4 = e4 & 31;
      uint2 u;
      u.x = pack_bf2(rbuf[j].x, rbuf[j].y);
      u.y = pack_bf2(rbuf[j].z, rbuf[j].w);
      *(uint2*)(&sh_x[row * 136 + c4 * 4]) = u;
    }
    __syncthreads();                            // barrier1

    if (i + 1 < ST_TPB) {
      const float4* Xv2 = (const float4*)(state + (size_t)(r0 + 32) * D_IN);
      rbuf[0] = Xv2[tid]; rbuf[1] = Xv2[tid + 512];
    }
    float fa = 0.f, fb = 0.f;
    if (tid < 256) { fa = action[r0 * 8 + tid]; fb = beta_lp[r0 * 8 + tid]; }

    if (role == 0) {
      // ---- critic GEMM + fused head
#pragma unroll
      for (int rt = 0; rt < 2; ++rt) {
        f32x4 acc[4];
#pragma unroll
        for (int ct = 0; ct < 4; ++ct) acc[ct] = (f32x4){0.f, 0.f, 0.f, 0.f};
#pragma unroll
        for (int ki = 0; ki < 4; ++ki) {
          short8 a = *(const short8*)(&sh_x[(rt * 16 + c) * 136 + ki * 32 + quad * 8]);
#pragma unroll
          for (int ct = 0; ct < 4; ++ct)
            acc[ct] = __builtin_amdgcn_mfma_f32_16x16x32_bf16(a, bfrag[ct][ki], acc[ct], 0, 0, 0);
        }
#pragma unroll
        for (int r = 0; r < 4; ++r) {
          float p = 0.f;
#pragma unroll
          for (int ct = 0; ct < 4; ++ct)
            p += tanh_pre(acc[ct][r] + bias_c[ct]) * wc2_c[ct];
          p = row16_sum(p);
          if (c == 15) sh_v[(rt * 16 + quad * 4 + r) * 4 + wl] = p;
        }
      }
    } else {
      // ---- actor GEMM -> sh_h
#pragma unroll
      for (int rt = 0; rt < 2; ++rt) {
        f32x4 acc[4];
#pragma unroll
        for (int ct = 0; ct < 4; ++ct) acc[ct] = (f32x4){0.f, 0.f, 0.f, 0.f};
#pragma unroll
        for (int ki = 0; ki < 4; ++ki) {
          short8 a = *(const short8*)(&sh_x[(rt * 16 + c) * 136 + ki * 32 + quad * 8]);
#pragma unroll
          for (int ct = 0; ct < 4; ++ct)
            acc[ct] = __builtin_amdgcn_mfma_f32_16x16x32_bf16(a, bfrag[ct][ki], acc[ct], 0, 0, 0);
        }
#pragma unroll
        for (int ct = 0; ct < 4; ++ct) {
          int col = wl * 64 + ct * 16 + c;
#pragma unroll
          for (int r = 0; r < 4; ++r) {
            int row = rt * 16 + quad * 4 + r;
            sh_h[row * 264 + col] = bf_trunc(tanh_pre(acc[ct][r] + bias_c[ct]));
          }
        }
      }
    }
    __syncthreads();                            // barrier2

    if (role == 1) {
      // ---- head GEMM: slice wl owns K-cols [wl*64, +64)
#pragma unroll
      for (int st = 0; st < 2; ++st) {
        f32x4 acc2 = (f32x4){0.f, 0.f, 0.f, 0.f};
#pragma unroll
        for (int k2 = 0; k2 < 2; ++k2) {
          int kofs = wl * 64 + k2 * 32 + quad * 8;
          short8 a2 = *(const short8*)(H1 + c * 256 + kofs);
          short8 b2 = *(const short8*)(&sh_h[(st * 16 + c) * 264 + kofs]);
          acc2 = __builtin_amdgcn_mfma_f32_16x16x32_bf16(a2, b2, acc2, 0, 0, 0);
        }
        *((f32x4*)&sh_hb[((wl * 32) + st * 16 + c) * HB_S + quad * 4]) = acc2;
      }
    } else if (tid < 32) {
      v0out[r0 + tid] = sh_v[tid * 4] + sh_v[tid * 4 + 1] + sh_v[tid * 4 + 2] +
                        sh_v[tid * 4 + 3] + vbias;
    }
    __syncthreads();                            // barrier3

    if (tid < 256) {
      int s = tid >> 3;
      float mu = sh_hb[(s)*HB_S + aa]            + sh_hb[(32 + s) * HB_S + aa] +
                 sh_hb[(64 + s) * HB_S + aa]     + sh_hb[(96 + s) * HB_S + aa] + bmu_a;
      float lv = sh_hb[(s)*HB_S + 8 + aa]        + sh_hb[(32 + s) * HB_S + 8 + aa] +
                 sh_hb[(64 + s) * HB_S + 8 + aa] + sh_hb[(96 + s) * HB_S + 8 + aa] + blv_a;
      float d = fa - mu;
      float term = -0.5f * d * d * __expf(-lv) - 0.5f * lv - HALF_LOG_2PI - fb;
      term = xor8_sum(term);
      if (aa == 0) ratio[r0 + s] = __expf(term);
    }
  }

  // ================= phase 2: next_state critic -> v1 =================
  const int wg  = wv >> 2;            // row half
  const int t0n = blockIdx.x * NX_TPB;

  float4 rbuf2[4];
  {
    const float4* Xv = (const float4*)(next_state + (size_t)t0n * 64 * D_IN);
#pragma unroll
    for (int j = 0; j < 4; ++j) rbuf2[j] = Xv[tid + j * 512];
  }
  if (role == 1) {
    // actor waves switch to critic weights for col-slice wl (L2-hot reload)
#pragma unroll
    for (int ct = 0; ct < 4; ++ct) {
      int n = wl * 64 + ct * 16 + c;
      bias_c[ct] = bc1[n] * SCALE2;
      wc2_c[ct]  = Wc2[n];
#pragma unroll
      for (int ki = 0; ki < 4; ++ki)
        bfrag[ct][ki] = *(const short8*)(Wc1Ts + n * 128 + ki * 32 + quad * 8);
    }
  }

  for (int i = 0; i < NX_TPB; ++i) {
    const int r0 = (t0n + i) * 64;
#pragma unroll
    for (int j = 0; j < 4; ++j) {
      int e4 = tid + j * 512;
      int row = e4 >> 5, c4 = e4 & 31;
      uint2 u;
      u.x = pack_bf2(rbuf2[j].x, rbuf2[j].y);
      u.y = pack_bf2(rbuf2[j].z, rbuf2[j].w);
      *(uint2*)(&sh_x2[row * 136 + c4 * 4]) = u;
    }
    __syncthreads();                            // barrier1

    if (i + 1 < NX_TPB) {
      const float4* Xv2 = (const float4*)(next_state + (size_t)(r0 + 64) * D_IN);
#pragma unroll
      for (int j = 0; j < 4; ++j) rbuf2[j] = Xv2[tid + j * 512];
    }

#pragma unroll
    for (int rt = 0; rt < 2; ++rt) {
      f32x4 acc[4];
#pragma unroll
      for (int ct = 0; ct < 4; ++ct) acc[ct] = (f32x4){0.f, 0.f, 0.f, 0.f};
#pragma unroll
      for (int ki = 0; ki < 4; ++ki) {
        short8 a = *(const short8*)(&sh_x2[(wg * 32 + rt * 16 + c) * 136 + ki * 32 + quad * 8]);
#pragma unroll
        for (int ct = 0; ct < 4; ++ct)
          acc[ct] = __builtin_amdgcn_mfma_f32_16x16x32_bf16(a, bfrag[ct][ki], acc[ct], 0, 0, 0);
      }
#pragma unroll
      for (int r = 0; r < 4; ++r) {
        float p = 0.f;
#pragma unroll
        for (int ct = 0; ct < 4; ++ct)
          p += tanh_pre(acc[ct][r] + bias_c[ct]) * wc2_c[ct];
        p = row16_sum(p);
        if (c == 15) sh_v2[(wg * 32 + rt * 16 + quad * 4 + r) * 4 + wl] = p;
      }
    }
    __syncthreads();                            // barrier2

    if (tid < 64)
      v1out[r0 + tid] = sh_v2[tid * 4] + sh_v2[tid * 4 + 1] + sh_v2[tid * 4 + 2] +
                        sh_v2[tid * 4 + 3] + vbias;
  }
}

// ---------------------------------------------------------------- GAE + losses, ONE kernel:
// 256 blocks (== CU count -> guaranteed co-resident; software grid barrier via
// device-scope counters). Each block: 1024 own elems + 1024 lookahead
// (c^1024 ~ 5e-28 -> exact truncation in fp32). adv stays in registers.
// Spin is RELAXED (measured null vs ACQUIRE-spin, kept for cleanliness).
__global__ __launch_bounds__(256) void k_gae2(
    const float* __restrict__ reward, const float* __restrict__ v0,
    const float* __restrict__ v1, const float* __restrict__ ratio,
    float* __restrict__ accs, float* __restrict__ out) {
  const int j = blockIdx.x, k = threadIdx.x;
  const int base = j * 1024 + k * 8;
  unsigned int* cnt1 = (unsigned int*)accs + 4;
  unsigned int* cnt2 = (unsigned int*)accs + 5;

  float d[8];
  float s = 0.f, w = 1.f;
#pragma unroll
  for (int i = 0; i < 8; ++i) {
    int idx = base + i;
    float dd = 0.f;
    if (idx < T_N) dd = reward[idx] + GAMMA * v1[idx] - v0[idx];
    d[i] = dd;
    s += w * dd;
    w *= C_GL;
  }
  const float W8 = w;
  __shared__ float Ss[256], Sw[256];
  __shared__ float sh_stats[2];
  Ss[k] = s; Sw[k] = W8;
  __syncthreads();
  for (int st = 1; st < 256; st <<= 1) {
    bool has = (k + st) < 256;
    float ns = 0.f, nw = 0.f;
    if (has) { ns = Ss[k] + Sw[k] * Ss[k + st]; nw = Sw[k] * Sw[k + st]; }
    __syncthreads();
    if (has) { Ss[k] = ns; Sw[k] = nw; }
    __syncthreads();
  }
  float g = (k < 255) ? Ss[k + 1] : 0.f;
  float adv[8];
  float sa = 0.f, sq = 0.f;
  if (k < 128) {
#pragma unroll
    for (int i = 7; i >= 0; --i) {
      g = d[i] + C_GL * g;
      float a = g - v0[base + i];
      adv[i] = a;
      sa += a; sq += a * a;
    }
  }
  __syncthreads();
  Ss[k] = sa; Sw[k] = sq;
  __syncthreads();
  for (int off = 128; off > 0; off >>= 1) {
    if (k < off) { Ss[k] += Ss[k + off]; Sw[k] += Sw[k + off]; }
    __syncthreads();
  }
  if (k == 0) {
    atomicAdd(&accs[0], Ss[0]);                 // Σ adv
    atomicAdd(&accs[1], Sw[0]);                 // Σ adv² (= critic_loss)
    __hip_atomic_fetch_add(cnt1, 1u, __ATOMIC_RELEASE, __HIP_MEMORY_SCOPE_AGENT);
    // ---- software grid barrier (256 blocks co-resident on 256 CUs)
    while (__hip_atomic_load(cnt1, __ATOMIC_RELAXED, __HIP_MEMORY_SCOPE_AGENT) < 256u)
      __builtin_amdgcn_s_sleep(16);
    (void)__hip_atomic_load(cnt1, __ATOMIC_ACQUIRE, __HIP_MEMORY_SCOPE_AGENT);
    sh_stats[0] = __hip_atomic_load(&accs[0], __ATOMIC_RELAXED, __HIP_MEMORY_SCOPE_AGENT);
    sh_stats[1] = __hip_atomic_load(&accs[1], __ATOMIC_RELAXED, __HIP_MEMORY_SCOPE_AGENT);
  }
  __syncthreads();

  const float sum  = sh_stats[0];
  const float cl   = sh_stats[1];
  const float mean = sum * (1.f / (float)T_N);
  const float var  = (cl - sum * mean) / (float)(T_N - 1);
  const float inv  = 1.f / (sqrtf(var) + 1e-7f);
  float sl = 0.f;
  if (k < 128) {
#pragma unroll
    for (int i = 0; i < 8; ++i) {
      float a = (adv[i] - mean) * inv;
      float r = ratio[base + i];
      float rc = fminf(fmaxf(r, 1.f - EPS_C), 1.f + EPS_C);
      sl += -fminf(r * a, rc * a);
    }
  }
  __syncthreads();
  Ss[k] = sl;
  __syncthreads();
  for (int off = 128; off > 0; off >>= 1) {
    if (k < off) Ss[k] += Ss[k + off];
    __syncthreads();
  }
  if (k == 0) {
    atomicAdd(&accs[2], Ss[0]);                 // actor_loss
    unsigned int old = __hip_atomic_fetch_add(cnt2, 1u, __ATOMIC_ACQ_REL,
                                              __HIP_MEMORY_SCOPE_AGENT);
    if (old == 255u) {
      float al = __hip_atomic_load(&accs[2], __ATOMIC_RELAXED, __HIP_MEMORY_SCOPE_AGENT);
      out[0] = al + cl;                         // actor_loss + critic_loss
    }
  }
}

// ---------------------------------------------------------------- launch
extern "C" void kernel_launch(void* const* d_in, const int* in_sizes, int n_in,
                              void* d_out, int out_size, void* d_ws, size_t ws_size,
                              hipStream_t stream) {
  const float* state      = (const float*)d_in[0];
  const float* next_state = (const float*)d_in[1];
  const float* action     = (const float*)d_in[2];
  const float* beta_lp    = (const float*)d_in[3];
  const float* reward     = (const float*)d_in[4];
  const float* W1   = (const float*)d_in[5];
  const float* b1   = (const float*)d_in[6];
  const float* Wmu  = (const float*)d_in[7];
  const float* bmu  = (const float*)d_in[8];
  const float* Wlv  = (const float*)d_in[9];
  const float* blv  = (const float*)d_in[10];
  const float* Wc1  = (const float*)d_in[11];
  const float* bc1  = (const float*)d_in[12];
  const float* Wc2  = (const float*)d_in[13];
  const float* bc2  = (const float*)d_in[14];

  char* ws = (char*)d_ws;
  size_t o = 0;
  unsigned short* Wc1Ts = (unsigned short*)(ws + o); o += 65536;
  unsigned short* W1Ts  = (unsigned short*)(ws + o); o += 65536;
  unsigned short* H1    = (unsigned short*)(ws + o); o += 8192;
  float* v0    = (float*)(ws + o); o += (size_t)T_N * 4;
  float* v1    = (float*)(ws + o); o += (size_t)T_N * 4;
  float* ratio = (float*)(ws + o); o += (size_t)T_N * 4;
  float* accs  = (float*)(ws + o); o += 256;

  k_prep<<<272, 256, 0, stream>>>(Wc1, W1, Wmu, Wlv, Wc1Ts, W1Ts, H1, accs);

  k_main<<<(T_N / 32) / ST_TPB, 512, 0, stream>>>(
      state, next_state, action, beta_lp, Wc1Ts, W1Ts, H1,
      bc1, b1, Wc2, bc2, bmu, blv, v0, v1, ratio);

  k_gae2<<<256, 256, 0, stream>>>(reward, v0, v1, ratio, accs, (float*)d_out);
}

// Round 16
// 367.706 us; speedup vs baseline: 1.0837x; 1.0837x over previous
//
#include <hip/hip_runtime.h>

// ---------------------------------------------------------------- constants
#define T_N   262144
#define D_IN  128
#define A_DIM 8
#define GAMMA 0.99f
#define EPS_C 0.2f
#define C_GL  0.9405f                 // GAMMA*LMBD
#define HALF_LOG_2PI 0.9189385332f
#define SCALE2 2.8853900817779268f    // 2*log2(e): pre-activation scale for exp2-tanh
#define ST_TPB 8                      // k_state tiles/block -> 1024 blocks (4/CU)
#define NX_TPB 4                      // k_next tiles/block  -> 2048 blocks (8/CU)
#define HB_S   20                     // sh_hb padded stride (floats)

typedef __attribute__((ext_vector_type(8))) short short8;
typedef __attribute__((ext_vector_type(4))) float f32x4;

__device__ __forceinline__ unsigned short f2bf(float f) {   // RNE (prep only)
  unsigned int u = __float_as_uint(f);
  u += 0x7FFFu + ((u >> 16) & 1u);
  return (unsigned short)(u >> 16);
}
// pack two f32 -> two bf16 (truncate) in ONE v_perm_b32
__device__ __forceinline__ unsigned int pack_bf2(float lo, float hi) {
  return __builtin_amdgcn_perm(__float_as_uint(hi), __float_as_uint(lo), 0x07060302u);
}
__device__ __forceinline__ unsigned short bf_trunc(float f) {
  return (unsigned short)(__float_as_uint(f) >> 16);
}
// a = 2*log2(e)*x (weights pre-scaled); returns tanh(x).
__device__ __forceinline__ float tanh_pre(float a) {
  float e = __builtin_amdgcn_exp2f(a);
  return 1.f - 2.f * __builtin_amdgcn_rcpf(e + 1.f);
}
template <int CTRL>
__device__ __forceinline__ float dpp_add(float p) {
  return p + __int_as_float(__builtin_amdgcn_update_dpp(
                 0, __float_as_int(p), CTRL, 0xF, 0xF, true));
}
// sum over each 16-lane row; total lands at lane%16 == 15
__device__ __forceinline__ float row16_sum(float p) {
  p = dpp_add<0x111>(p); p = dpp_add<0x112>(p);
  p = dpp_add<0x114>(p); p = dpp_add<0x118>(p);
  return p;
}
// sum over each 8-lane group; total at all 8 lanes (xor1, xor2, half-mirror)
__device__ __forceinline__ float xor8_sum(float p) {
  p = dpp_add<0xB1>(p); p = dpp_add<0x4E>(p); p = dpp_add<0x141>(p);
  return p;
}

// ---------------------------------------------------------------- prep:
// Wc1Ts/W1Ts: [H][D] bf16, transposed AND pre-scaled by 2*log2(e).
// H1: [16][256] bf16 actor head (rows0-7 = Wmu^T, 8-15 = Wlv^T). Also zeros accs.
__global__ __launch_bounds__(256) void k_prep(
    const float* __restrict__ Wc1, const float* __restrict__ W1,
    const float* __restrict__ Wmu, const float* __restrict__ Wlv,
    unsigned short* __restrict__ Wc1Ts, unsigned short* __restrict__ W1Ts,
    unsigned short* __restrict__ H1, float* __restrict__ accs) {
  int i = blockIdx.x * 256 + threadIdx.x;
  if (blockIdx.x == 0 && threadIdx.x < 8) ((unsigned int*)accs)[threadIdx.x] = 0u;
  if (i < 32768) {
    int n = i >> 7, k = i & 127;
    Wc1Ts[i] = f2bf(Wc1[k * 256 + n] * SCALE2);
  } else if (i < 65536) {
    int j = i - 32768; int n = j >> 7, k = j & 127;
    W1Ts[j] = f2bf(W1[k * 256 + n] * SCALE2);
  } else if (i < 69632) {
    int j = i - 65536; int h = j >> 8, n = j & 255;
    H1[j] = (h < 8) ? f2bf(Wmu[n * 8 + h]) : f2bf(Wlv[n * 8 + (h - 8)]);
  }
}

// ---------------------------------------------------------------- k_state:
// R0-exact structure (measured 93 us twice): 1024 persistent blocks x ST_TPB
// tiles of 32 rows; 512 threads. waves 0-3: critic(state)->v0; waves 4-7:
// actor hidden -> head MFMA (4-way K-split) -> sh_hb -> 256-thread ratio
// epilogue. 3 barriers/tile. Role balance + early action/beta loads measured
// essential (R7: -52 us when violated). Do not restructure (R2/R4/R7/R13 all
// regressed).
__global__ __launch_bounds__(512, 4) void k_state(
    const float* __restrict__ state,
    const float* __restrict__ action, const float* __restrict__ beta_lp,
    const unsigned short* __restrict__ Wc1Ts, const unsigned short* __restrict__ W1Ts,
    const unsigned short* __restrict__ H1,
    const float* __restrict__ bc1, const float* __restrict__ b1,
    const float* __restrict__ Wc2, const float* __restrict__ bc2,
    const float* __restrict__ bmu, const float* __restrict__ blv,
    float* __restrict__ v0out, float* __restrict__ ratio) {
  const int tid  = threadIdx.x;
  const int lane = tid & 63;
  const int wv   = tid >> 6;          // 0..7
  const int role = wv >> 2;           // 0 = critic, 1 = actor
  const int wl   = wv & 3;            // slice within role
  const int c    = lane & 15;
  const int quad = lane >> 4;

  __shared__ unsigned short sh_x[32 * 136];   // 8.5 KB
  __shared__ unsigned short sh_h[32 * 264];   // 16.5 KB
  __shared__ float sh_hb[4 * 32 * HB_S];      // 10 KB, padded stride
  __shared__ float sh_v[32 * 4];

  const unsigned short* WT = role ? W1Ts : Wc1Ts;
  const float* bias = role ? b1 : bc1;

  short8 bfrag[4][4];
  float bias_c[4], wc2_c[4];
#pragma unroll
  for (int ct = 0; ct < 4; ++ct) {
    int n = wl * 64 + ct * 16 + c;
    bias_c[ct] = bias[n] * SCALE2;
    wc2_c[ct]  = Wc2[n];
#pragma unroll
    for (int ki = 0; ki < 4; ++ki)
      bfrag[ct][ki] = *(const short8*)(WT + n * 128 + ki * 32 + quad * 8);
  }
  const float vbias = bc2[0];
  const int aa = tid & 7;
  const float bmu_a = bmu[aa], blv_a = blv[aa];

  const int t0 = blockIdx.x * ST_TPB;

  float4 rbuf[2];
  {
    const float4* Xv = (const float4*)(state + (size_t)t0 * 32 * D_IN);
    rbuf[0] = Xv[tid]; rbuf[1] = Xv[tid + 512];
  }

  for (int i = 0; i < ST_TPB; ++i) {
    const int r0 = (t0 + i) * 32;

    // ---- stage regs -> LDS bf16 (perm-truncate: 1 op / 2 elems)
#pragma unroll
    for (int j = 0; j < 2; ++j) {
      int e4 = tid + j * 512;
      int row = e4 >> 5, c4 = e4 & 31;
      uint2 u;
      u.x = pack_bf2(rbuf[j].x, rbuf[j].y);
      u.y = pack_bf2(rbuf[j].z, rbuf[j].w);
      *(uint2*)(&sh_x[row * 136 + c4 * 4]) = u;
    }
    __syncthreads();                            // barrier1

    if (i + 1 < ST_TPB) {
      const float4* Xv2 = (const float4*)(state + (size_t)(r0 + 32) * D_IN);
      rbuf[0] = Xv2[tid]; rbuf[1] = Xv2[tid + 512];
    }
    float fa = 0.f, fb = 0.f;
    if (tid < 256) { fa = action[r0 * 8 + tid]; fb = beta_lp[r0 * 8 + tid]; }

    if (role == 0) {
      // ---- critic GEMM + fused head
#pragma unroll
      for (int rt = 0; rt < 2; ++rt) {
        f32x4 acc[4];
#pragma unroll
        for (int ct = 0; ct < 4; ++ct) acc[ct] = (f32x4){0.f, 0.f, 0.f, 0.f};
#pragma unroll
        for (int ki = 0; ki < 4; ++ki) {
          short8 a = *(const short8*)(&sh_x[(rt * 16 + c) * 136 + ki * 32 + quad * 8]);
#pragma unroll
          for (int ct = 0; ct < 4; ++ct)
            acc[ct] = __builtin_amdgcn_mfma_f32_16x16x32_bf16(a, bfrag[ct][ki], acc[ct], 0, 0, 0);
        }
#pragma unroll
        for (int r = 0; r < 4; ++r) {
          float p = 0.f;
#pragma unroll
          for (int ct = 0; ct < 4; ++ct)
            p += tanh_pre(acc[ct][r] + bias_c[ct]) * wc2_c[ct];
          p = row16_sum(p);
          if (c == 15) sh_v[(rt * 16 + quad * 4 + r) * 4 + wl] = p;
        }
      }
    } else {
      // ---- actor GEMM -> sh_h
#pragma unroll
      for (int rt = 0; rt < 2; ++rt) {
        f32x4 acc[4];
#pragma unroll
        for (int ct = 0; ct < 4; ++ct) acc[ct] = (f32x4){0.f, 0.f, 0.f, 0.f};
#pragma unroll
        for (int ki = 0; ki < 4; ++ki) {
          short8 a = *(const short8*)(&sh_x[(rt * 16 + c) * 136 + ki * 32 + quad * 8]);
#pragma unroll
          for (int ct = 0; ct < 4; ++ct)
            acc[ct] = __builtin_amdgcn_mfma_f32_16x16x32_bf16(a, bfrag[ct][ki], acc[ct], 0, 0, 0);
        }
#pragma unroll
        for (int ct = 0; ct < 4; ++ct) {
          int col = wl * 64 + ct * 16 + c;
#pragma unroll
          for (int r = 0; r < 4; ++r) {
            int row = rt * 16 + quad * 4 + r;
            sh_h[row * 264 + col] = bf_trunc(tanh_pre(acc[ct][r] + bias_c[ct]));
          }
        }
      }
    }
    __syncthreads();                            // barrier2

    if (role == 1) {
      // ---- head GEMM: slice wl owns K-cols [wl*64, +64)
#pragma unroll
      for (int st = 0; st < 2; ++st) {
        f32x4 acc2 = (f32x4){0.f, 0.f, 0.f, 0.f};
#pragma unroll
        for (int k2 = 0; k2 < 2; ++k2) {
          int kofs = wl * 64 + k2 * 32 + quad * 8;
          short8 a2 = *(const short8*)(H1 + c * 256 + kofs);
          short8 b2 = *(const short8*)(&sh_h[(st * 16 + c) * 264 + kofs]);
          acc2 = __builtin_amdgcn_mfma_f32_16x16x32_bf16(a2, b2, acc2, 0, 0, 0);
        }
        *((f32x4*)&sh_hb[((wl * 32) + st * 16 + c) * HB_S + quad * 4]) = acc2;
      }
    } else if (tid < 32) {
      v0out[r0 + tid] = sh_v[tid * 4] + sh_v[tid * 4 + 1] + sh_v[tid * 4 + 2] +
                        sh_v[tid * 4 + 3] + vbias;
    }
    __syncthreads();                            // barrier3

    if (tid < 256) {
      int s = tid >> 3;
      float mu = sh_hb[(s)*HB_S + aa]            + sh_hb[(32 + s) * HB_S + aa] +
                 sh_hb[(64 + s) * HB_S + aa]     + sh_hb[(96 + s) * HB_S + aa] + bmu_a;
      float lv = sh_hb[(s)*HB_S + 8 + aa]        + sh_hb[(32 + s) * HB_S + 8 + aa] +
                 sh_hb[(64 + s) * HB_S + 8 + aa] + sh_hb[(96 + s) * HB_S + 8 + aa] + blv_a;
      float d = fa - mu;
      float term = -0.5f * d * d * __expf(-lv) - 0.5f * lv - HALF_LOG_2PI - fb;
      term = xor8_sum(term);
      if (aa == 0) ratio[r0 + s] = __expf(term);
    }
  }
}

// ---------------------------------------------------------------- k_next:
// critic(next_state) -> v1. 2048 persistent blocks x NX_TPB tiles; 256 threads.
__global__ __launch_bounds__(256, 4) void k_next(
    const float* __restrict__ next_state,
    const unsigned short* __restrict__ Wc1Ts,
    const float* __restrict__ bc1, const float* __restrict__ Wc2,
    const float* __restrict__ bc2, float* __restrict__ v1out) {
  const int tid = threadIdx.x;
  const int lane = tid & 63;
  const int wv   = tid >> 6;
  const int c    = lane & 15;
  const int quad = lane >> 4;

  __shared__ unsigned short sh_x[32 * 136];
  __shared__ float sh_v[32 * 4];

  short8 bfrag[4][4];
  float bias_c[4], wc2_c[4];
#pragma unroll
  for (int ct = 0; ct < 4; ++ct) {
    int n = wv * 64 + ct * 16 + c;
    bias_c[ct] = bc1[n] * SCALE2;
    wc2_c[ct]  = Wc2[n];
#pragma unroll
    for (int ki = 0; ki < 4; ++ki)
      bfrag[ct][ki] = *(const short8*)(Wc1Ts + n * 128 + ki * 32 + quad * 8);
  }
  const float vbias = bc2[0];

  const int t0 = blockIdx.x * NX_TPB;
  float4 rbuf[4];
  {
    const float4* Xv = (const float4*)(next_state + (size_t)t0 * 32 * D_IN);
#pragma unroll
    for (int j = 0; j < 4; ++j) rbuf[j] = Xv[tid + j * 256];
  }

  for (int i = 0; i < NX_TPB; ++i) {
    const int r0 = (t0 + i) * 32;
#pragma unroll
    for (int j = 0; j < 4; ++j) {
      int e = tid + j * 256;
      int row = e >> 5, c4 = e & 31;
      uint2 u;
      u.x = pack_bf2(rbuf[j].x, rbuf[j].y);
      u.y = pack_bf2(rbuf[j].z, rbuf[j].w);
      *(uint2*)(&sh_x[row * 136 + c4 * 4]) = u;
    }
    __syncthreads();

    if (i + 1 < NX_TPB) {
      const float4* Xv2 = (const float4*)(next_state + (size_t)(r0 + 32) * D_IN);
#pragma unroll
      for (int j = 0; j < 4; ++j) rbuf[j] = Xv2[tid + j * 256];
    }

#pragma unroll
    for (int rt = 0; rt < 2; ++rt) {
      f32x4 acc[4];
#pragma unroll
      for (int ct = 0; ct < 4; ++ct) acc[ct] = (f32x4){0.f, 0.f, 0.f, 0.f};
#pragma unroll
      for (int ki = 0; ki < 4; ++ki) {
        short8 a = *(const short8*)(&sh_x[(rt * 16 + c) * 136 + ki * 32 + quad * 8]);
#pragma unroll
        for (int ct = 0; ct < 4; ++ct)
          acc[ct] = __builtin_amdgcn_mfma_f32_16x16x32_bf16(a, bfrag[ct][ki], acc[ct], 0, 0, 0);
      }
#pragma unroll
      for (int r = 0; r < 4; ++r) {
        float p = 0.f;
#pragma unroll
        for (int ct = 0; ct < 4; ++ct)
          p += tanh_pre(acc[ct][r] + bias_c[ct]) * wc2_c[ct];
        p = row16_sum(p);
        if (c == 15) sh_v[(rt * 16 + quad * 4 + r) * 4 + wv] = p;
      }
    }
    __syncthreads();
    if (tid < 32) {
      v1out[r0 + tid] = sh_v[tid * 4] + sh_v[tid * 4 + 1] + sh_v[tid * 4 + 2] +
                        sh_v[tid * 4 + 3] + vbias;
    }
  }
}

// ---------------------------------------------------------------- GAE pass 1:
// 256 blocks x 256 threads, NO grid barrier. Each block: 1024 own elems +
// 1024 lookahead (c^1024 ~ 5e-28 -> exact truncation in fp32) -> adv to ws,
// block-reduced (Σadv, Σadv²) -> atomics. Barrier-free: the old in-kernel
// spin made gae2's span = straggler-arrival + work; a kernel boundary
// (measured free, R13) replaces it.
__global__ __launch_bounds__(256) void k_gae_scan(
    const float* __restrict__ reward, const float* __restrict__ v0,
    const float* __restrict__ v1, float* __restrict__ adv_out,
    float* __restrict__ accs) {
  const int j = blockIdx.x, k = threadIdx.x;
  const int base = j * 1024 + k * 8;

  float d[8];
  float s = 0.f, w = 1.f;
#pragma unroll
  for (int i = 0; i < 8; ++i) {
    int idx = base + i;
    float dd = 0.f;
    if (idx < T_N) dd = reward[idx] + GAMMA * v1[idx] - v0[idx];
    d[i] = dd;
    s += w * dd;
    w *= C_GL;
  }
  const float W8 = w;
  __shared__ float Ss[256], Sw[256];
  Ss[k] = s; Sw[k] = W8;
  __syncthreads();
  for (int st = 1; st < 256; st <<= 1) {
    bool has = (k + st) < 256;
    float ns = 0.f, nw = 0.f;
    if (has) { ns = Ss[k] + Sw[k] * Ss[k + st]; nw = Sw[k] * Sw[k + st]; }
    __syncthreads();
    if (has) { Ss[k] = ns; Sw[k] = nw; }
    __syncthreads();
  }
  float g = (k < 255) ? Ss[k + 1] : 0.f;
  float adv[8];
  float sa = 0.f, sq = 0.f;
  if (k < 128) {
#pragma unroll
    for (int i = 7; i >= 0; --i) {
      g = d[i] + C_GL * g;
      float a = g - v0[base + i];
      adv[i] = a;
      sa += a; sq += a * a;
    }
    *(float4*)(adv_out + base)     = make_float4(adv[0], adv[1], adv[2], adv[3]);
    *(float4*)(adv_out + base + 4) = make_float4(adv[4], adv[5], adv[6], adv[7]);
  }
  __syncthreads();
  Ss[k] = sa; Sw[k] = sq;
  __syncthreads();
  for (int off = 128; off > 0; off >>= 1) {
    if (k < off) { Ss[k] += Ss[k + off]; Sw[k] += Sw[k + off]; }
    __syncthreads();
  }
  if (k == 0) {
    atomicAdd(&accs[0], Ss[0]);                 // Σ adv
    atomicAdd(&accs[1], Sw[0]);                 // Σ adv² (= critic_loss)
  }
}

// ---------------------------------------------------------------- GAE pass 2:
// 256 blocks x 256 threads, 4 elems/thread. Kernel boundary guarantees the
// stats in accs are final. Clipped actor loss; last finisher writes out.
__global__ __launch_bounds__(256) void k_loss(
    const float* __restrict__ adv_in, const float* __restrict__ ratio,
    float* __restrict__ accs, float* __restrict__ out) {
  const int j = blockIdx.x, k = threadIdx.x;
  const int base = j * 1024 + k * 4;
  unsigned int* cnt2 = (unsigned int*)accs + 5;

  const float sum  = accs[0];
  const float cl   = accs[1];
  const float mean = sum * (1.f / (float)T_N);
  const float var  = (cl - sum * mean) / (float)(T_N - 1);
  const float inv  = 1.f / (sqrtf(var) + 1e-7f);

  float4 a4 = *(const float4*)(adv_in + base);
  float4 r4 = *(const float4*)(ratio  + base);
  float sl = 0.f;
#pragma unroll
  for (int i = 0; i < 4; ++i) {
    float a = (((const float*)&a4)[i] - mean) * inv;
    float r = ((const float*)&r4)[i];
    float rc = fminf(fmaxf(r, 1.f - EPS_C), 1.f + EPS_C);
    sl += -fminf(r * a, rc * a);
  }
  __shared__ float Ss[256];
  Ss[k] = sl;
  __syncthreads();
  for (int off = 128; off > 0; off >>= 1) {
    if (k < off) Ss[k] += Ss[k + off];
    __syncthreads();
  }
  if (k == 0) {
    atomicAdd(&accs[2], Ss[0]);                 // actor_loss
    unsigned int old = __hip_atomic_fetch_add(cnt2, 1u, __ATOMIC_ACQ_REL,
                                              __HIP_MEMORY_SCOPE_AGENT);
    if (old == 255u) {
      float al = __hip_atomic_load(&accs[2], __ATOMIC_RELAXED, __HIP_MEMORY_SCOPE_AGENT);
      out[0] = al + cl;                         // actor_loss + critic_loss
    }
  }
}

// ---------------------------------------------------------------- launch
extern "C" void kernel_launch(void* const* d_in, const int* in_sizes, int n_in,
                              void* d_out, int out_size, void* d_ws, size_t ws_size,
                              hipStream_t stream) {
  const float* state      = (const float*)d_in[0];
  const float* next_state = (const float*)d_in[1];
  const float* action     = (const float*)d_in[2];
  const float* beta_lp    = (const float*)d_in[3];
  const float* reward     = (const float*)d_in[4];
  const float* W1   = (const float*)d_in[5];
  const float* b1   = (const float*)d_in[6];
  const float* Wmu  = (const float*)d_in[7];
  const float* bmu  = (const float*)d_in[8];
  const float* Wlv  = (const float*)d_in[9];
  const float* blv  = (const float*)d_in[10];
  const float* Wc1  = (const float*)d_in[11];
  const float* bc1  = (const float*)d_in[12];
  const float* Wc2  = (const float*)d_in[13];
  const float* bc2  = (const float*)d_in[14];

  char* ws = (char*)d_ws;
  size_t o = 0;
  unsigned short* Wc1Ts = (unsigned short*)(ws + o); o += 65536;
  unsigned short* W1Ts  = (unsigned short*)(ws + o); o += 65536;
  unsigned short* H1    = (unsigned short*)(ws + o); o += 8192;
  float* v0    = (float*)(ws + o); o += (size_t)T_N * 4;
  float* v1    = (float*)(ws + o); o += (size_t)T_N * 4;
  float* ratio = (float*)(ws + o); o += (size_t)T_N * 4;
  float* advb  = (float*)(ws + o); o += (size_t)T_N * 4;
  float* accs  = (float*)(ws + o); o += 256;

  k_prep<<<272, 256, 0, stream>>>(Wc1, W1, Wmu, Wlv, Wc1Ts, W1Ts, H1, accs);

  k_state<<<(T_N / 32) / ST_TPB, 512, 0, stream>>>(
      state, action, beta_lp, Wc1Ts, W1Ts, H1, bc1, b1, Wc2, bc2, bmu, blv,
      v0, ratio);
  k_next<<<(T_N / 32) / NX_TPB, 256, 0, stream>>>(
      next_state, Wc1Ts, bc1, Wc2, bc2, v1);
  k_gae_scan<<<256, 256, 0, stream>>>(reward, v0, v1, advb, accs);
  k_loss<<<256, 256, 0, stream>>>(advb, ratio, accs, (float*)d_out);
}